// Round 11
// baseline (668.473 us; speedup 1.0000x reference)
//
#include <hip/hip_runtime.h>
#include <type_traits>
#include <utility>

typedef __attribute__((ext_vector_type(4))) float f32x4;
typedef __attribute__((ext_vector_type(8))) short short8v;
typedef __attribute__((ext_vector_type(8))) unsigned short ushort8v;
typedef __attribute__((ext_vector_type(8))) __bf16 bf16x8;

template<typename T, typename = void> struct can_mfma : std::false_type {};
template<typename T> struct can_mfma<T, std::void_t<decltype(
  __builtin_amdgcn_mfma_f32_16x16x32_bf16(std::declval<T>(), std::declval<T>(),
                                          std::declval<f32x4>(), 0, 0, 0))>>
  : std::true_type {};
using frag_t = std::conditional_t<can_mfma<short8v>::value, short8v, bf16x8>;

__device__ __forceinline__ f32x4 MFMA(frag_t a, frag_t b, f32x4 c){
  return __builtin_amdgcn_mfma_f32_16x16x32_bf16(a, b, c, 0, 0, 0);
}

__device__ __forceinline__ unsigned short bfrn(float x){
  unsigned u = __float_as_uint(x);
  return (unsigned short)((u + 0x7FFFu + ((u >> 16) & 1u)) >> 16);
}
__device__ __forceinline__ float bf2f(unsigned short h){
  return __uint_as_float(((unsigned)h) << 16);
}
__device__ __forceinline__ float lrelu(float v){ return v > 0.f ? v : 0.2f*v; }
__device__ __forceinline__ void add4(float4& a, const float4 v){
  a.x += v.x; a.y += v.y; a.z += v.z; a.w += v.w; }
__device__ __forceinline__ void fma4(float4& a, float w, const float4 v){
  a.x += w*v.x; a.y += w*v.y; a.z += w*v.z; a.w += w*v.w; }
__device__ __forceinline__ void mul4(float4& a, float w){
  a.x *= w; a.y *= w; a.z *= w; a.w *= w; }

// split 8 fp32 -> hi/lo bf16 fragments
__device__ __forceinline__ void split8(const float* vals, frag_t& fh, frag_t& fl){
  union { unsigned short u[8]; ushort8v v; } Uh, Ul;
#pragma unroll
  for (int j = 0; j < 8; j++){
    unsigned short hb = bfrn(vals[j]);
    Uh.u[j] = hb;
    Ul.u[j] = bfrn(vals[j] - bf2f(hb));
  }
  fh = __builtin_bit_cast(frag_t, Uh.v);
  fl = __builtin_bit_cast(frag_t, Ul.v);
}

// ================= CSR build =================
__global__ void deg_count(const int* __restrict__ dst, int* __restrict__ deg, int E){
  int e = blockIdx.x*blockDim.x + threadIdx.x;
  if (e < E) atomicAdd(&deg[dst[e]], 1);
}

__global__ void scan_block(const int* __restrict__ deg, int* __restrict__ rowptr,
                           int* __restrict__ bsum){
  __shared__ int s[256];
  int t = threadIdx.x; int i = blockIdx.x*256 + t;
  int v = deg[i];
  s[t] = v; __syncthreads();
  for (int off=1; off<256; off<<=1){
    int a = (t>=off)? s[t-off] : 0; __syncthreads();
    s[t] += a; __syncthreads();
  }
  rowptr[i+1] = s[t];
  if (t==255) bsum[blockIdx.x] = s[255];
}

__global__ void scan_top(int* __restrict__ bsum){
  __shared__ int s[256];
  int t = threadIdx.x;
  int v0=bsum[t*4], v1=bsum[t*4+1], v2=bsum[t*4+2], v3=bsum[t*4+3];
  s[t] = v0+v1+v2+v3; __syncthreads();
  for (int off=1; off<256; off<<=1){
    int a = (t>=off)? s[t-off] : 0; __syncthreads();
    s[t] += a; __syncthreads();
  }
  int excl = (t==0)? 0 : s[t-1];
  bsum[t*4]   = excl;
  bsum[t*4+1] = excl+v0;
  bsum[t*4+2] = excl+v0+v1;
  bsum[t*4+3] = excl+v0+v1+v2;
}

// adds block offsets AND mirrors rowptr into wp (fill cursor) in one pass
__global__ void scan_add_wp(int* __restrict__ rowptr, int* __restrict__ wp,
                            const int* __restrict__ bsum){
  int i = blockIdx.x*256 + threadIdx.x;
  int v = rowptr[i+1] + bsum[blockIdx.x];
  rowptr[i+1] = v;
  wp[i+1] = v;
  if (i == 0){ rowptr[0] = 0; wp[0] = 0; }
}

__global__ void fill_csr(const int* __restrict__ src, const int* __restrict__ dst,
                         int* __restrict__ wp, int* __restrict__ col, int E){
  int e = blockIdx.x*blockDim.x + threadIdx.x;
  if (e < E){
    int d = dst[e];
    int pos = atomicAdd(&wp[d], 1);
    __builtin_nontemporal_store(src[e], &col[pos]);
  }
}

// ================= weight pre-split: fp32 -> bf16 hi/lo =================
// 0..16383 sage_Wl | ..32767 sage_Wr | ..45055 gat_W | ..49151 p1W | ..51199 p2W | ..51711 p3W
__global__ void prep_weights(const float* __restrict__ Wl, const float* __restrict__ Wr,
                             const float* __restrict__ Wg, const float* __restrict__ P1,
                             const float* __restrict__ P2, const float* __restrict__ P3,
                             unsigned short* __restrict__ hi, unsigned short* __restrict__ lo){
  int i = blockIdx.x*256 + threadIdx.x;
  if (i >= 51712) return;
  float v;
  if (i < 16384) v = Wl[i];
  else if (i < 32768) v = Wr[i-16384];
  else if (i < 45056) v = Wg[i-32768];
  else if (i < 49152) v = P1[i-45056];
  else if (i < 51200) v = P2[i-49152];
  else v = P3[i-51200];
  unsigned short hb = bfrn(v);
  hi[i] = hb;
  lo[i] = bfrn(v - bf2f(hb));
}

// ================= SAGE: gather-mean + split-bf16 MFMA (LDS-staged weights) ====
__global__ __launch_bounds__(256,3) void sage_mfma(
    const float* __restrict__ cur, const int* __restrict__ rowptr,
    const int* __restrict__ col,
    const unsigned short* __restrict__ WlHi, const unsigned short* __restrict__ WlLo,
    const unsigned short* __restrict__ WrHi, const unsigned short* __restrict__ WrLo,
    const float* __restrict__ bias, float* __restrict__ out, int do_relu){
  __shared__ __align__(16) unsigned short sMhi[64*64];
  __shared__ __align__(16) unsigned short sMlo[64*64];
  __shared__ __align__(16) unsigned short sW[4][4096]; // 4 x 8KB
  int t = threadIdx.x;
  int row0 = blockIdx.x * 64;
  int w = t >> 6, l = t & 63;
  int lr = l & 15, lg = l >> 4;
  // ---- stage 4 weight planes into LDS, swizzled (overlaps with gather below;
  //      single barrier before MFMA covers all LDS deps) ----
  {
    const ushort8v* g0 = (const ushort8v*)WlHi;
    const ushort8v* g1 = (const ushort8v*)WlLo;
    const ushort8v* g2 = (const ushort8v*)WrHi;
    const ushort8v* g3 = (const ushort8v*)WrLo;
#pragma unroll
    for (int i = 0; i < 2; i++){
      int c = t + i*256;
      int row = c >> 3, slot = c & 7;
      int addr = row*64 + ((slot ^ (row & 7)) << 3);
      *(ushort8v*)&sW[0][addr] = g0[c];
      *(ushort8v*)&sW[1][addr] = g1[c];
      *(ushort8v*)&sW[2][addr] = g2[c];
      *(ushort8v*)&sW[3][addr] = g3[c];
    }
  }
  // ---- gather-mean: 8 lanes/row x 8 feats, 4-edge predicated chunks ----
  {
    int o = l & 7;
    int rw = l >> 3;
    const float4* base4 = (const float4*)cur;
#pragma unroll
    for (int p = 0; p < 2; p++){
      int r = p*32 + w*8 + rw;
      int row = row0 + r;
      int beg = rowptr[row], end = rowptr[row+1];   // L2-hot, wave-broadcast
      float4 a0 = {0,0,0,0}, a1 = a0;
      for (int j = beg; j < end; j += 4){
        int e1i = end - 1;
        int i1 = j+1 < end ? j+1 : e1i;
        int i2 = j+2 < end ? j+2 : e1i;
        int i3 = j+3 < end ? j+3 : e1i;
        int s0 = col[j], s1 = col[i1], s2 = col[i2], s3 = col[i3];
        float w1 = (j+1<end)?1.f:0.f, w2=(j+2<end)?1.f:0.f, w3=(j+3<end)?1.f:0.f;
        const float4* p0 = base4 + (size_t)s0*16 + o*2;
        const float4* p1 = base4 + (size_t)s1*16 + o*2;
        const float4* p2 = base4 + (size_t)s2*16 + o*2;
        const float4* p3 = base4 + (size_t)s3*16 + o*2;
        float4 q00=p0[0], q01=p0[1], q10=p1[0], q11=p1[1];
        float4 q20=p2[0], q21=p2[1], q30=p3[0], q31=p3[1];
        add4(a0,q00);    add4(a1,q01);
        fma4(a0,w1,q10); fma4(a1,w1,q11);
        fma4(a0,w2,q20); fma4(a1,w2,q21);
        fma4(a0,w3,q30); fma4(a1,w3,q31);
      }
      float rdeg = 1.f / fmaxf((float)(end-beg), 1.f);
      mul4(a0,rdeg); mul4(a1,rdeg);
      float mv[8];
      *(float4*)&mv[0] = a0; *(float4*)&mv[4] = a1;
      union { unsigned short u[8]; ushort8v v; } Uh, Ul;
#pragma unroll
      for (int j2 = 0; j2 < 8; j2++){
        unsigned short hb = bfrn(mv[j2]);
        Uh.u[j2] = hb;
        Ul.u[j2] = bfrn(mv[j2] - bf2f(hb));
      }
      int slot = o ^ (r & 7);
      *(ushort8v*)&sMhi[r*64 + slot*8] = Uh.v;
      *(ushort8v*)&sMlo[r*64 + slot*8] = Ul.v;
    }
  }
  // ---- A-x fragments: own row slice from global (L2/L3-warm) ----
  frag_t ax_hi[2], ax_lo[2];
  {
    int grow = row0 + w*16 + lr;
#pragma unroll
    for (int kt = 0; kt < 2; kt++){
      float vals[8];
      const float* p = cur + (size_t)grow*64 + kt*32 + lg*8;
      *(float4*)&vals[0] = *(const float4*)p;
      *(float4*)&vals[4] = *(const float4*)(p + 4);
      split8(vals, ax_hi[kt], ax_lo[kt]);
    }
  }
  __syncthreads();
  // ---- MFMA GEMM ----
  int rl = (w << 4) + lr;
  frag_t am_hi[2], am_lo[2];
#pragma unroll
  for (int kt = 0; kt < 2; kt++){
    int slot = (kt*4 + lg) ^ (rl & 7);
    am_hi[kt] = __builtin_bit_cast(frag_t, *(const ushort8v*)&sMhi[rl*64 + slot*8]);
    am_lo[kt] = __builtin_bit_cast(frag_t, *(const ushort8v*)&sMlo[rl*64 + slot*8]);
  }
#pragma unroll
  for (int ct = 0; ct < 4; ct++){
    float bv = bias[ct*16 + lr];
    f32x4 acc = {bv, bv, bv, bv};
    int wrow = ct*16 + lr;
#pragma unroll
    for (int kt = 0; kt < 2; kt++){
      int sl = wrow*64 + (((kt*4 + lg) ^ (wrow & 7)) << 3);
      frag_t blh = __builtin_bit_cast(frag_t, *(const ushort8v*)&sW[0][sl]);
      frag_t bll = __builtin_bit_cast(frag_t, *(const ushort8v*)&sW[1][sl]);
      acc = MFMA(am_hi[kt], blh, acc);
      acc = MFMA(am_lo[kt], blh, acc);
      acc = MFMA(am_hi[kt], bll, acc);
      frag_t brh = __builtin_bit_cast(frag_t, *(const ushort8v*)&sW[2][sl]);
      frag_t brl = __builtin_bit_cast(frag_t, *(const ushort8v*)&sW[3][sl]);
      acc = MFMA(ax_hi[kt], brh, acc);
      acc = MFMA(ax_lo[kt], brh, acc);
      acc = MFMA(ax_hi[kt], brl, acc);
    }
#pragma unroll
    for (int r = 0; r < 4; r++){
      float v = acc[r];
      if (do_relu) v = fmaxf(v, 0.f);
      out[(size_t)(row0 + w*16 + lg*4 + r)*64 + ct*16 + lr] = v;
    }
  }
}

// ================= GAT: split-bf16 MFMA GEMM (LDS weights) + attention dots ====
__global__ __launch_bounds__(256,8) void gat_mfma(
    const float* __restrict__ cur,
    const unsigned short* __restrict__ WHi, const unsigned short* __restrict__ WLo,
    const float* __restrict__ a_src, const float* __restrict__ a_dst,
    float* __restrict__ h, float* __restrict__ asv, float* __restrict__ adv){
  __shared__ __align__(16) unsigned short sW[2][4096];
  int t = threadIdx.x;
  int row0 = blockIdx.x * 64;
  int w = t >> 6, l = t & 63;
  int lr = l & 15, lg = l >> 4;
  {
    const ushort8v* g0 = (const ushort8v*)WHi;
    const ushort8v* g1 = (const ushort8v*)WLo;
#pragma unroll
    for (int i = 0; i < 2; i++){
      int c = t + i*256;
      int row = c >> 3, slot = c & 7;
      int addr = row*64 + ((slot ^ (row & 7)) << 3);
      *(ushort8v*)&sW[0][addr] = g0[c];
      *(ushort8v*)&sW[1][addr] = g1[c];
    }
  }
  frag_t ax_hi[2], ax_lo[2];
  {
    int grow = row0 + w*16 + lr;
#pragma unroll
    for (int kt = 0; kt < 2; kt++){
      float vals[8];
      const float* p = cur + (size_t)grow*64 + kt*32 + lg*8;
      *(float4*)&vals[0] = *(const float4*)p;
      *(float4*)&vals[4] = *(const float4*)(p + 4);
      split8(vals, ax_hi[kt], ax_lo[kt]);
    }
  }
  __syncthreads();
  float pav[4] = {0,0,0,0}, pdv[4] = {0,0,0,0};
#pragma unroll
  for (int ct = 0; ct < 4; ct++){
    f32x4 acc = {0,0,0,0};
    int wrow = ct*16 + lr;
#pragma unroll
    for (int kt = 0; kt < 2; kt++){
      int sl = wrow*64 + (((kt*4 + lg) ^ (wrow & 7)) << 3);
      frag_t bh = __builtin_bit_cast(frag_t, *(const ushort8v*)&sW[0][sl]);
      frag_t bl = __builtin_bit_cast(frag_t, *(const ushort8v*)&sW[1][sl]);
      acc = MFMA(ax_hi[kt], bh, acc);
      acc = MFMA(ax_lo[kt], bh, acc);
      acc = MFMA(ax_hi[kt], bl, acc);
    }
    float asc = a_src[ct*16 + lr], adc = a_dst[ct*16 + lr];
#pragma unroll
    for (int r = 0; r < 4; r++){
      float v = acc[r];
      h[(size_t)(row0 + w*16 + lg*4 + r)*64 + ct*16 + lr] = v;
      pav[r] += v * asc;
      pdv[r] += v * adc;
    }
  }
#pragma unroll
  for (int off = 1; off < 16; off <<= 1){
#pragma unroll
    for (int r = 0; r < 4; r++){
      pav[r] += __shfl_xor(pav[r], off);
      pdv[r] += __shfl_xor(pdv[r], off);
    }
  }
  if (lr == 0){
#pragma unroll
    for (int r = 0; r < 4; r++){
      int row = row0 + w*16 + lg*4 + r;
      asv[row] = pav[r];
      adv[row] = pdv[r];
    }
  }
}

// ================= GAT fused softmax-aggregate (inline asv logits, no LDS) =====
__global__ __launch_bounds__(256,6) void gat_agg(
    const float* __restrict__ h, const int* __restrict__ rowptr,
    const int* __restrict__ col, const float* __restrict__ asv,
    const float* __restrict__ adv, const float* __restrict__ bias,
    float* __restrict__ out, int do_relu){
  int t = threadIdx.x;
  int row0 = blockIdx.x * 32;
  int rl = t >> 3;
  int o = t & 7;
  int v = row0 + rl;
  int beg = rowptr[v], end = rowptr[v+1];   // L2-hot, 8-lane broadcast
  float advv = adv[v];
  float m = lrelu(asv[v] + advv);
  float den = 1.f;
  const float4* hb4 = (const float4*)h;
  const float4* pv = hb4 + (size_t)v*16 + o*2;
  float4 a0 = pv[0], a1 = pv[1];
  for (int j = beg; j < end; j += 4){
    int e1i = end - 1;
    int i1 = j+1 < end ? j+1 : e1i;
    int i2 = j+2 < end ? j+2 : e1i;
    int i3 = j+3 < end ? j+3 : e1i;
    int s0 = col[j], s1 = col[i1], s2 = col[i2], s3 = col[i3];
    float q1 = (j+1<end)?1.f:0.f, q2=(j+2<end)?1.f:0.f, q3=(j+3<end)?1.f:0.f;
    float e0 = lrelu(asv[s0] + advv);
    float e1 = lrelu(asv[s1] + advv);
    float e2 = lrelu(asv[s2] + advv);
    float e3 = lrelu(asv[s3] + advv);
    float cm = fmaxf(fmaxf(e0, e1), fmaxf(e2, e3));
    if (cm > m){
      float sc = expf(m - cm);
      den *= sc; mul4(a0, sc); mul4(a1, sc);
      m = cm;
    }
    float w0 = expf(e0 - m);
    float w1 = q1 * expf(e1 - m);
    float w2 = q2 * expf(e2 - m);
    float w3 = q3 * expf(e3 - m);
    den += w0 + w1 + w2 + w3;
    const float4* p0 = hb4 + (size_t)s0*16 + o*2;
    const float4* p1 = hb4 + (size_t)s1*16 + o*2;
    const float4* p2 = hb4 + (size_t)s2*16 + o*2;
    const float4* p3 = hb4 + (size_t)s3*16 + o*2;
    float4 g00=p0[0], g01=p0[1], g10=p1[0], g11=p1[1];
    float4 g20=p2[0], g21=p2[1], g30=p3[0], g31=p3[1];
    fma4(a0,w0,g00); fma4(a1,w0,g01);
    fma4(a0,w1,g10); fma4(a1,w1,g11);
    fma4(a0,w2,g20); fma4(a1,w2,g21);
    fma4(a0,w3,g30); fma4(a1,w3,g31);
  }
  float rden = 1.f / fmaxf(den, 1e-16f);
  const float4* b4 = (const float4*)bias;
  float4 bb0 = b4[o*2], bb1 = b4[o*2+1];
  mul4(a0,rden); mul4(a1,rden);
  add4(a0,bb0); add4(a1,bb1);
  if (do_relu){
    a0.x=fmaxf(a0.x,0.f); a0.y=fmaxf(a0.y,0.f); a0.z=fmaxf(a0.z,0.f); a0.w=fmaxf(a0.w,0.f);
    a1.x=fmaxf(a1.x,0.f); a1.y=fmaxf(a1.y,0.f); a1.z=fmaxf(a1.z,0.f); a1.w=fmaxf(a1.w,0.f);
  }
  float4* o4 = (float4*)out + (size_t)v*16 + o*2;
  o4[0] = a0; o4[1] = a1;
}

// ================= fused MLP 64->64->32->16, split-bf16 MFMA =================
__global__ __launch_bounds__(256,3) void mlp3(
    const float* __restrict__ in,
    const unsigned short* __restrict__ W1Hi, const unsigned short* __restrict__ W1Lo,
    const unsigned short* __restrict__ W2Hi, const unsigned short* __restrict__ W2Lo,
    const unsigned short* __restrict__ W3Hi, const unsigned short* __restrict__ W3Lo,
    const float* __restrict__ b1, const float* __restrict__ b2,
    const float* __restrict__ b3, float* __restrict__ out){
  __shared__ __align__(16) unsigned short sW1[2][4096];
  __shared__ __align__(16) unsigned short sW2[2][2048];
  __shared__ __align__(16) unsigned short sW3[2][512];
  __shared__ float sH1[64*68];
  __shared__ float sH2[64*36];
  int t = threadIdx.x;
  int row0 = blockIdx.x * 64;
  int w = t >> 6, l = t & 63;
  int lr = l & 15, lg = l >> 4;
  {
#pragma unroll
    for (int i = 0; i < 2; i++){
      int c = t + i*256;
      int row = c >> 3, slot = c & 7;
      int addr = row*64 + ((slot ^ (row & 7)) << 3);
      *(ushort8v*)&sW1[0][addr] = ((const ushort8v*)W1Hi)[c];
      *(ushort8v*)&sW1[1][addr] = ((const ushort8v*)W1Lo)[c];
    }
    {
      int c = t;
      int row = c >> 3, slot = c & 7;
      int addr = row*64 + ((slot ^ (row & 7)) << 3);
      *(ushort8v*)&sW2[0][addr] = ((const ushort8v*)W2Hi)[c];
      *(ushort8v*)&sW2[1][addr] = ((const ushort8v*)W2Lo)[c];
    }
    if (t < 64){
      int row = t >> 2, slot = t & 3;
      int addr = row*32 + ((slot ^ (row & 3)) << 3);
      *(ushort8v*)&sW3[0][addr] = ((const ushort8v*)W3Hi)[t];
      *(ushort8v*)&sW3[1][addr] = ((const ushort8v*)W3Lo)[t];
    }
  }
  frag_t ax_hi[2], ax_lo[2];
  {
    int grow = row0 + w*16 + lr;
#pragma unroll
    for (int kt = 0; kt < 2; kt++){
      float vals[8];
      const float* p = in + (size_t)grow*64 + kt*32 + lg*8;
      *(float4*)&vals[0] = *(const float4*)p;
      *(float4*)&vals[4] = *(const float4*)(p + 4);
      split8(vals, ax_hi[kt], ax_lo[kt]);
    }
  }
  __syncthreads();
#pragma unroll
  for (int ct = 0; ct < 4; ct++){
    int wrow = ct*16 + lr;
    float bv = b1[wrow];
    f32x4 acc = {bv, bv, bv, bv};
#pragma unroll
    for (int kt = 0; kt < 2; kt++){
      int sl = wrow*64 + (((kt*4 + lg) ^ (wrow & 7)) << 3);
      frag_t bh = __builtin_bit_cast(frag_t, *(const ushort8v*)&sW1[0][sl]);
      frag_t bl = __builtin_bit_cast(frag_t, *(const ushort8v*)&sW1[1][sl]);
      acc = MFMA(ax_hi[kt], bh, acc);
      acc = MFMA(ax_lo[kt], bh, acc);
      acc = MFMA(ax_hi[kt], bl, acc);
    }
#pragma unroll
    for (int r = 0; r < 4; r++)
      sH1[(w*16 + lg*4 + r)*68 + wrow] = fmaxf(acc[r], 0.f);
  }
  frag_t a2_hi[2], a2_lo[2];
#pragma unroll
  for (int kt = 0; kt < 2; kt++){
    float vals[8];
    const float* p = &sH1[(w*16 + lr)*68 + kt*32 + lg*8];
    *(float4*)&vals[0] = *(const float4*)p;
    *(float4*)&vals[4] = *(const float4*)(p + 4);
    split8(vals, a2_hi[kt], a2_lo[kt]);
  }
#pragma unroll
  for (int ct = 0; ct < 2; ct++){
    int wrow = ct*16 + lr;
    float bv = b2[wrow];
    f32x4 acc = {bv, bv, bv, bv};
#pragma unroll
    for (int kt = 0; kt < 2; kt++){
      int sl = wrow*64 + (((kt*4 + lg) ^ (wrow & 7)) << 3);
      frag_t bh = __builtin_bit_cast(frag_t, *(const ushort8v*)&sW2[0][sl]);
      frag_t bl = __builtin_bit_cast(frag_t, *(const ushort8v*)&sW2[1][sl]);
      acc = MFMA(a2_hi[kt], bh, acc);
      acc = MFMA(a2_lo[kt], bh, acc);
      acc = MFMA(a2_hi[kt], bl, acc);
    }
#pragma unroll
    for (int r = 0; r < 4; r++)
      sH2[(w*16 + lg*4 + r)*36 + wrow] = fmaxf(acc[r], 0.f);
  }
  frag_t a3_hi, a3_lo;
  {
    float vals[8];
    const float* p = &sH2[(w*16 + lr)*36 + lg*8];
    *(float4*)&vals[0] = *(const float4*)p;
    *(float4*)&vals[4] = *(const float4*)(p + 4);
    split8(vals, a3_hi, a3_lo);
  }
  {
    float bv = b3[lr];
    f32x4 acc = {bv, bv, bv, bv};
    int sl = lr*32 + ((lg ^ (lr & 3)) << 3);
    frag_t bh = __builtin_bit_cast(frag_t, *(const ushort8v*)&sW3[0][sl]);
    frag_t bl = __builtin_bit_cast(frag_t, *(const ushort8v*)&sW3[1][sl]);
    acc = MFMA(a3_hi, bh, acc);
    acc = MFMA(a3_lo, bh, acc);
    acc = MFMA(a3_hi, bl, acc);
#pragma unroll
    for (int r = 0; r < 4; r++)
      out[(size_t)(row0 + w*16 + lg*4 + r)*16 + lr] = acc[r];
  }
}

extern "C" void kernel_launch(void* const* d_in, const int* in_sizes, int n_in,
                              void* d_out, int out_size, void* d_ws, size_t ws_size,
                              hipStream_t stream) {
    const float* x        = (const float*)d_in[0];
    const int*   ei       = (const int*)d_in[1];
    const float* sage_Wl  = (const float*)d_in[2];
    const float* sage_Wr  = (const float*)d_in[3];
    const float* sage_b   = (const float*)d_in[4];
    const float* gat_W    = (const float*)d_in[5];
    const float* gat_as   = (const float*)d_in[6];
    const float* gat_ad   = (const float*)d_in[7];
    const float* gat_b    = (const float*)d_in[8];
    const float* p1W = (const float*)d_in[9],  *p1b = (const float*)d_in[10];
    const float* p2W = (const float*)d_in[11], *p2b = (const float*)d_in[12];
    const float* p3W = (const float*)d_in[13], *p3b = (const float*)d_in[14];

    int n = in_sizes[0] / 64;        // 262144
    int E = in_sizes[1] / 2;         // 1048576
    const int* src = ei;
    const int* dst = ei + E;

    size_t N64 = (size_t)n * 64;
    float* bufA   = (float*)d_ws;
    float* bufB   = bufA + N64;
    int*   rowptr = (int*)(bufB + N64);          // n+4 ints
    int*   wp     = rowptr + (n + 4);            // n+4; reused for weights after CSR? no: whi after wp
    int*   col    = wp + (n + 4);
    int*   bsum   = col + E;
    float* asv    = (float*)(bsum + 1024);
    float* adv    = asv + n;

    unsigned short* whi = (unsigned short*)(adv + n);
    unsigned short* wlo = whi + 51712;

    int nb = n / 256;                 // 1024

    // ---- CSR build ----
    hipMemsetAsync(wp, 0, (size_t)n * 4, stream);
    deg_count<<<(E + 255) / 256, 256, 0, stream>>>(dst, wp, E);
    scan_block<<<nb, 256, 0, stream>>>(wp, rowptr, bsum);
    scan_top<<<1, 256, 0, stream>>>(bsum);
    scan_add_wp<<<nb, 256, 0, stream>>>(rowptr, wp, bsum);
    fill_csr<<<(E + 255) / 256, 256, 0, stream>>>(src, dst, wp, col, E);

    // ---- weight pre-split ----
    prep_weights<<<202, 256, 0, stream>>>(sage_Wl, sage_Wr, gat_W, p1W, p2W, p3W,
                                          whi, wlo);

    // ---- 4 SAGE layers ----
    const float* cur = x;
    float* nxt = bufA;
    for (int l = 0; l < 4; l++){
        sage_mfma<<<n / 64, 256, 0, stream>>>(cur, rowptr, col,
            whi + l*4096,          wlo + l*4096,
            whi + 16384 + l*4096,  wlo + 16384 + l*4096,
            sage_b + l*64, nxt, l < 3 ? 1 : 0);
        cur = nxt;
        nxt = (nxt == bufA) ? bufB : bufA;
    }
    // cur = bufB, h buffer = bufA

    // ---- 3 GAT layers ----
    for (int l = 0; l < 3; l++){
        gat_mfma<<<n / 64, 256, 0, stream>>>(cur,
            whi + 32768 + l*4096, wlo + 32768 + l*4096,
            gat_as + l*64, gat_ad + l*64, nxt, asv, adv);
        gat_agg<<<n / 32, 256, 0, stream>>>(nxt, rowptr, col, asv, adv,
            gat_b + l*64, (float*)cur, l < 2 ? 1 : 0);
    }

    // ---- projection MLP (split-bf16 MFMA) ----
    mlp3<<<n / 64, 256, 0, stream>>>(cur,
        whi + 45056, wlo + 45056,
        whi + 49152, wlo + 49152,
        whi + 51200, wlo + 51200,
        p1b, p2b, p3b, (float*)d_out);
}

// Round 12
// 586.537 us; speedup vs baseline: 1.1397x; 1.1397x over previous
//
#include <hip/hip_runtime.h>
#include <type_traits>
#include <utility>

typedef __attribute__((ext_vector_type(4))) float f32x4;
typedef __attribute__((ext_vector_type(8))) short short8v;
typedef __attribute__((ext_vector_type(8))) unsigned short ushort8v;
typedef __attribute__((ext_vector_type(8))) __bf16 bf16x8;

template<typename T, typename = void> struct can_mfma : std::false_type {};
template<typename T> struct can_mfma<T, std::void_t<decltype(
  __builtin_amdgcn_mfma_f32_16x16x32_bf16(std::declval<T>(), std::declval<T>(),
                                          std::declval<f32x4>(), 0, 0, 0))>>
  : std::true_type {};
using frag_t = std::conditional_t<can_mfma<short8v>::value, short8v, bf16x8>;

__device__ __forceinline__ f32x4 MFMA(frag_t a, frag_t b, f32x4 c){
  return __builtin_amdgcn_mfma_f32_16x16x32_bf16(a, b, c, 0, 0, 0);
}

__device__ __forceinline__ unsigned short bfrn(float x){
  unsigned u = __float_as_uint(x);
  return (unsigned short)((u + 0x7FFFu + ((u >> 16) & 1u)) >> 16);
}
__device__ __forceinline__ float bf2f(unsigned short h){
  return __uint_as_float(((unsigned)h) << 16);
}
__device__ __forceinline__ float lrelu(float v){ return v > 0.f ? v : 0.2f*v; }
__device__ __forceinline__ void add4(float4& a, const float4 v){
  a.x += v.x; a.y += v.y; a.z += v.z; a.w += v.w; }
__device__ __forceinline__ void fma4(float4& a, float w, const float4 v){
  a.x += w*v.x; a.y += w*v.y; a.z += w*v.z; a.w += w*v.w; }
__device__ __forceinline__ void mul4(float4& a, float w){
  a.x *= w; a.y *= w; a.z *= w; a.w *= w; }

// split 8 fp32 -> hi/lo bf16 fragments
__device__ __forceinline__ void split8(const float* vals, frag_t& fh, frag_t& fl){
  union { unsigned short u[8]; ushort8v v; } Uh, Ul;
#pragma unroll
  for (int j = 0; j < 8; j++){
    unsigned short hb = bfrn(vals[j]);
    Uh.u[j] = hb;
    Ul.u[j] = bfrn(vals[j] - bf2f(hb));
  }
  fh = __builtin_bit_cast(frag_t, Uh.v);
  fl = __builtin_bit_cast(frag_t, Ul.v);
}

// ================= CSR build: locality-bucketed (256 buckets x 1024 nodes) ====
// record = src | ((dst & 1023) << 18)   (n = 2^18)

__global__ void bucket_hist(const int* __restrict__ dst, int* __restrict__ bcnt, int E){
  __shared__ int h[256];
  int t = threadIdx.x;
  h[t] = 0; __syncthreads();
  int base = blockIdx.x * 4096;
#pragma unroll
  for (int i = 0; i < 16; i++){
    int e = base + t + i*256;
    if (e < E) atomicAdd(&h[dst[e] >> 10], 1);
  }
  __syncthreads();
  atomicAdd(&bcnt[t], h[t]);
}

__global__ void bucket_scan(const int* __restrict__ bcnt, int* __restrict__ boff,
                            int* __restrict__ bcur){
  __shared__ int s[256];
  int t = threadIdx.x;
  int v = bcnt[t];
  s[t] = v; __syncthreads();
  for (int off=1; off<256; off<<=1){
    int a = (t>=off)? s[t-off] : 0; __syncthreads();
    s[t] += a; __syncthreads();
  }
  boff[t+1] = s[t];
  bcur[t] = s[t] - v;
  if (t == 0) boff[0] = 0;
}

__global__ void bucket_scatter(const int* __restrict__ src, const int* __restrict__ dst,
                               int* __restrict__ bcur, unsigned* __restrict__ rec, int E){
  __shared__ int h[256], hb[256];
  int t = threadIdx.x;
  h[t] = 0; __syncthreads();
  int base = blockIdx.x * 4096;
#pragma unroll
  for (int i = 0; i < 16; i++){
    int e = base + t + i*256;
    if (e < E) atomicAdd(&h[dst[e] >> 10], 1);
  }
  __syncthreads();
  hb[t] = atomicAdd(&bcur[t], h[t]);
  h[t] = 0;
  __syncthreads();
#pragma unroll
  for (int i = 0; i < 16; i++){
    int e = base + t + i*256;
    if (e < E){
      int d = dst[e];
      int b = d >> 10;
      int lp = atomicAdd(&h[b], 1);
      rec[hb[b] + lp] = (unsigned)src[e] | ((unsigned)(d & 1023) << 18);
    }
  }
}

// one block per bucket: per-node counts -> LDS scan -> rowptr + in-window scatter
__global__ __launch_bounds__(256) void bucket_fill(
    const unsigned* __restrict__ rec, const int* __restrict__ boff,
    int* __restrict__ rowptr, int* __restrict__ col){
  __shared__ int cnt[1024];
  __shared__ int stmp[256];
  int t = threadIdx.x;
  int b = blockIdx.x;
  int base = boff[b];
  int m = boff[b+1] - base;
#pragma unroll
  for (int i = 0; i < 4; i++) cnt[t*4+i] = 0;
  __syncthreads();
  for (int j = t; j < m; j += 256)
    atomicAdd(&cnt[rec[base+j] >> 18], 1);
  __syncthreads();
  int c0=cnt[t*4], c1=cnt[t*4+1], c2=cnt[t*4+2], c3=cnt[t*4+3];
  int s = c0+c1+c2+c3;
  stmp[t] = s; __syncthreads();
  for (int off=1; off<256; off<<=1){
    int a = (t>=off)? stmp[t-off] : 0; __syncthreads();
    stmp[t] += a; __syncthreads();
  }
  int excl = stmp[t] - s;
  int e0 = excl, e1 = e0+c0, e2 = e1+c1, e3 = e2+c2;
  cnt[t*4]=e0; cnt[t*4+1]=e1; cnt[t*4+2]=e2; cnt[t*4+3]=e3;
  int vbase = b*1024 + t*4;
  rowptr[vbase+1] = base + e1;
  rowptr[vbase+2] = base + e2;
  rowptr[vbase+3] = base + e3;
  rowptr[vbase+4] = base + e3 + c3;
  if (b == 0 && t == 0) rowptr[0] = 0;
  __syncthreads();
  for (int j = t; j < m; j += 256){
    unsigned r = rec[base+j];
    int d = r >> 18;
    int p = atomicAdd(&cnt[d], 1);
    col[base + p] = (int)(r & 0x3FFFFu);
  }
}

// ================= weight pre-split: fp32 -> bf16 hi/lo =================
__global__ void prep_weights(const float* __restrict__ Wl, const float* __restrict__ Wr,
                             const float* __restrict__ Wg, const float* __restrict__ P1,
                             const float* __restrict__ P2, const float* __restrict__ P3,
                             unsigned short* __restrict__ hi, unsigned short* __restrict__ lo){
  int i = blockIdx.x*256 + threadIdx.x;
  if (i >= 51712) return;
  float v;
  if (i < 16384) v = Wl[i];
  else if (i < 32768) v = Wr[i-16384];
  else if (i < 45056) v = Wg[i-32768];
  else if (i < 49152) v = P1[i-45056];
  else if (i < 51200) v = P2[i-49152];
  else v = P3[i-51200];
  unsigned short hb = bfrn(v);
  hi[i] = hb;
  lo[i] = bfrn(v - bf2f(hb));
}

// ================= SAGE: gather-mean + split-bf16 MFMA (LDS-staged weights) ====
__global__ __launch_bounds__(256,3) void sage_mfma(
    const float* __restrict__ cur, const int* __restrict__ rowptr,
    const int* __restrict__ col,
    const unsigned short* __restrict__ WlHi, const unsigned short* __restrict__ WlLo,
    const unsigned short* __restrict__ WrHi, const unsigned short* __restrict__ WrLo,
    const float* __restrict__ bias, float* __restrict__ out, int do_relu){
  __shared__ __align__(16) unsigned short sMhi[64*64];
  __shared__ __align__(16) unsigned short sMlo[64*64];
  __shared__ __align__(16) unsigned short sW[4][4096];
  int t = threadIdx.x;
  int row0 = blockIdx.x * 64;
  int w = t >> 6, l = t & 63;
  int lr = l & 15, lg = l >> 4;
  {
    const ushort8v* g0 = (const ushort8v*)WlHi;
    const ushort8v* g1 = (const ushort8v*)WlLo;
    const ushort8v* g2 = (const ushort8v*)WrHi;
    const ushort8v* g3 = (const ushort8v*)WrLo;
#pragma unroll
    for (int i = 0; i < 2; i++){
      int c = t + i*256;
      int row = c >> 3, slot = c & 7;
      int addr = row*64 + ((slot ^ (row & 7)) << 3);
      *(ushort8v*)&sW[0][addr] = g0[c];
      *(ushort8v*)&sW[1][addr] = g1[c];
      *(ushort8v*)&sW[2][addr] = g2[c];
      *(ushort8v*)&sW[3][addr] = g3[c];
    }
  }
  {
    int o = l & 7;
    int rw = l >> 3;
    const float4* base4 = (const float4*)cur;
#pragma unroll
    for (int p = 0; p < 2; p++){
      int r = p*32 + w*8 + rw;
      int row = row0 + r;
      int beg = rowptr[row], end = rowptr[row+1];
      float4 a0 = {0,0,0,0}, a1 = a0;
      for (int j = beg; j < end; j += 4){
        int e1i = end - 1;
        int i1 = j+1 < end ? j+1 : e1i;
        int i2 = j+2 < end ? j+2 : e1i;
        int i3 = j+3 < end ? j+3 : e1i;
        int s0 = col[j], s1 = col[i1], s2 = col[i2], s3 = col[i3];
        float w1 = (j+1<end)?1.f:0.f, w2=(j+2<end)?1.f:0.f, w3=(j+3<end)?1.f:0.f;
        const float4* p0 = base4 + (size_t)s0*16 + o*2;
        const float4* p1 = base4 + (size_t)s1*16 + o*2;
        const float4* p2 = base4 + (size_t)s2*16 + o*2;
        const float4* p3 = base4 + (size_t)s3*16 + o*2;
        float4 q00=p0[0], q01=p0[1], q10=p1[0], q11=p1[1];
        float4 q20=p2[0], q21=p2[1], q30=p3[0], q31=p3[1];
        add4(a0,q00);    add4(a1,q01);
        fma4(a0,w1,q10); fma4(a1,w1,q11);
        fma4(a0,w2,q20); fma4(a1,w2,q21);
        fma4(a0,w3,q30); fma4(a1,w3,q31);
      }
      float rdeg = 1.f / fmaxf((float)(end-beg), 1.f);
      mul4(a0,rdeg); mul4(a1,rdeg);
      float mv[8];
      *(float4*)&mv[0] = a0; *(float4*)&mv[4] = a1;
      union { unsigned short u[8]; ushort8v v; } Uh, Ul;
#pragma unroll
      for (int j2 = 0; j2 < 8; j2++){
        unsigned short hb = bfrn(mv[j2]);
        Uh.u[j2] = hb;
        Ul.u[j2] = bfrn(mv[j2] - bf2f(hb));
      }
      int slot = o ^ (r & 7);
      *(ushort8v*)&sMhi[r*64 + slot*8] = Uh.v;
      *(ushort8v*)&sMlo[r*64 + slot*8] = Ul.v;
    }
  }
  frag_t ax_hi[2], ax_lo[2];
  {
    int grow = row0 + w*16 + lr;
#pragma unroll
    for (int kt = 0; kt < 2; kt++){
      float vals[8];
      const float* p = cur + (size_t)grow*64 + kt*32 + lg*8;
      *(float4*)&vals[0] = *(const float4*)p;
      *(float4*)&vals[4] = *(const float4*)(p + 4);
      split8(vals, ax_hi[kt], ax_lo[kt]);
    }
  }
  __syncthreads();
  int rl = (w << 4) + lr;
  frag_t am_hi[2], am_lo[2];
#pragma unroll
  for (int kt = 0; kt < 2; kt++){
    int slot = (kt*4 + lg) ^ (rl & 7);
    am_hi[kt] = __builtin_bit_cast(frag_t, *(const ushort8v*)&sMhi[rl*64 + slot*8]);
    am_lo[kt] = __builtin_bit_cast(frag_t, *(const ushort8v*)&sMlo[rl*64 + slot*8]);
  }
#pragma unroll
  for (int ct = 0; ct < 4; ct++){
    float bv = bias[ct*16 + lr];
    f32x4 acc = {bv, bv, bv, bv};
    int wrow = ct*16 + lr;
#pragma unroll
    for (int kt = 0; kt < 2; kt++){
      int sl = wrow*64 + (((kt*4 + lg) ^ (wrow & 7)) << 3);
      frag_t blh = __builtin_bit_cast(frag_t, *(const ushort8v*)&sW[0][sl]);
      frag_t bll = __builtin_bit_cast(frag_t, *(const ushort8v*)&sW[1][sl]);
      acc = MFMA(am_hi[kt], blh, acc);
      acc = MFMA(am_lo[kt], blh, acc);
      acc = MFMA(am_hi[kt], bll, acc);
      frag_t brh = __builtin_bit_cast(frag_t, *(const ushort8v*)&sW[2][sl]);
      frag_t brl = __builtin_bit_cast(frag_t, *(const ushort8v*)&sW[3][sl]);
      acc = MFMA(ax_hi[kt], brh, acc);
      acc = MFMA(ax_lo[kt], brh, acc);
      acc = MFMA(ax_hi[kt], brl, acc);
    }
#pragma unroll
    for (int r = 0; r < 4; r++){
      float v = acc[r];
      if (do_relu) v = fmaxf(v, 0.f);
      out[(size_t)(row0 + w*16 + lg*4 + r)*64 + ct*16 + lr] = v;
    }
  }
}

// ================= GAT: split-bf16 MFMA GEMM (LDS weights) + attention dots ====
__global__ __launch_bounds__(256,8) void gat_mfma(
    const float* __restrict__ cur,
    const unsigned short* __restrict__ WHi, const unsigned short* __restrict__ WLo,
    const float* __restrict__ a_src, const float* __restrict__ a_dst,
    float* __restrict__ h, float* __restrict__ asv, float* __restrict__ adv){
  __shared__ __align__(16) unsigned short sW[2][4096];
  int t = threadIdx.x;
  int row0 = blockIdx.x * 64;
  int w = t >> 6, l = t & 63;
  int lr = l & 15, lg = l >> 4;
  {
    const ushort8v* g0 = (const ushort8v*)WHi;
    const ushort8v* g1 = (const ushort8v*)WLo;
#pragma unroll
    for (int i = 0; i < 2; i++){
      int c = t + i*256;
      int row = c >> 3, slot = c & 7;
      int addr = row*64 + ((slot ^ (row & 7)) << 3);
      *(ushort8v*)&sW[0][addr] = g0[c];
      *(ushort8v*)&sW[1][addr] = g1[c];
    }
  }
  frag_t ax_hi[2], ax_lo[2];
  {
    int grow = row0 + w*16 + lr;
#pragma unroll
    for (int kt = 0; kt < 2; kt++){
      float vals[8];
      const float* p = cur + (size_t)grow*64 + kt*32 + lg*8;
      *(float4*)&vals[0] = *(const float4*)p;
      *(float4*)&vals[4] = *(const float4*)(p + 4);
      split8(vals, ax_hi[kt], ax_lo[kt]);
    }
  }
  __syncthreads();
  float pav[4] = {0,0,0,0}, pdv[4] = {0,0,0,0};
#pragma unroll
  for (int ct = 0; ct < 4; ct++){
    f32x4 acc = {0,0,0,0};
    int wrow = ct*16 + lr;
#pragma unroll
    for (int kt = 0; kt < 2; kt++){
      int sl = wrow*64 + (((kt*4 + lg) ^ (wrow & 7)) << 3);
      frag_t bh = __builtin_bit_cast(frag_t, *(const ushort8v*)&sW[0][sl]);
      frag_t bl = __builtin_bit_cast(frag_t, *(const ushort8v*)&sW[1][sl]);
      acc = MFMA(ax_hi[kt], bh, acc);
      acc = MFMA(ax_lo[kt], bh, acc);
      acc = MFMA(ax_hi[kt], bl, acc);
    }
    float asc = a_src[ct*16 + lr], adc = a_dst[ct*16 + lr];
#pragma unroll
    for (int r = 0; r < 4; r++){
      float v = acc[r];
      h[(size_t)(row0 + w*16 + lg*4 + r)*64 + ct*16 + lr] = v;
      pav[r] += v * asc;
      pdv[r] += v * adc;
    }
  }
#pragma unroll
  for (int off = 1; off < 16; off <<= 1){
#pragma unroll
    for (int r = 0; r < 4; r++){
      pav[r] += __shfl_xor(pav[r], off);
      pdv[r] += __shfl_xor(pdv[r], off);
    }
  }
  if (lr == 0){
#pragma unroll
    for (int r = 0; r < 4; r++){
      int row = row0 + w*16 + lg*4 + r;
      asv[row] = pav[r];
      adv[row] = pdv[r];
    }
  }
}

// ================= GAT fused softmax-aggregate (inline asv logits, no LDS) =====
__global__ __launch_bounds__(256,6) void gat_agg(
    const float* __restrict__ h, const int* __restrict__ rowptr,
    const int* __restrict__ col, const float* __restrict__ asv,
    const float* __restrict__ adv, const float* __restrict__ bias,
    float* __restrict__ out, int do_relu){
  int t = threadIdx.x;
  int row0 = blockIdx.x * 32;
  int rl = t >> 3;
  int o = t & 7;
  int v = row0 + rl;
  int beg = rowptr[v], end = rowptr[v+1];
  float advv = adv[v];
  float m = lrelu(asv[v] + advv);
  float den = 1.f;
  const float4* hb4 = (const float4*)h;
  const float4* pv = hb4 + (size_t)v*16 + o*2;
  float4 a0 = pv[0], a1 = pv[1];
  for (int j = beg; j < end; j += 4){
    int e1i = end - 1;
    int i1 = j+1 < end ? j+1 : e1i;
    int i2 = j+2 < end ? j+2 : e1i;
    int i3 = j+3 < end ? j+3 : e1i;
    int s0 = col[j], s1 = col[i1], s2 = col[i2], s3 = col[i3];
    float q1 = (j+1<end)?1.f:0.f, q2=(j+2<end)?1.f:0.f, q3=(j+3<end)?1.f:0.f;
    float e0 = lrelu(asv[s0] + advv);
    float e1 = lrelu(asv[s1] + advv);
    float e2 = lrelu(asv[s2] + advv);
    float e3 = lrelu(asv[s3] + advv);
    float cm = fmaxf(fmaxf(e0, e1), fmaxf(e2, e3));
    if (cm > m){
      float sc = expf(m - cm);
      den *= sc; mul4(a0, sc); mul4(a1, sc);
      m = cm;
    }
    float w0 = expf(e0 - m);
    float w1 = q1 * expf(e1 - m);
    float w2 = q2 * expf(e2 - m);
    float w3 = q3 * expf(e3 - m);
    den += w0 + w1 + w2 + w3;
    const float4* p0 = hb4 + (size_t)s0*16 + o*2;
    const float4* p1 = hb4 + (size_t)s1*16 + o*2;
    const float4* p2 = hb4 + (size_t)s2*16 + o*2;
    const float4* p3 = hb4 + (size_t)s3*16 + o*2;
    float4 g00=p0[0], g01=p0[1], g10=p1[0], g11=p1[1];
    float4 g20=p2[0], g21=p2[1], g30=p3[0], g31=p3[1];
    fma4(a0,w0,g00); fma4(a1,w0,g01);
    fma4(a0,w1,g10); fma4(a1,w1,g11);
    fma4(a0,w2,g20); fma4(a1,w2,g21);
    fma4(a0,w3,g30); fma4(a1,w3,g31);
  }
  float rden = 1.f / fmaxf(den, 1e-16f);
  const float4* b4 = (const float4*)bias;
  float4 bb0 = b4[o*2], bb1 = b4[o*2+1];
  mul4(a0,rden); mul4(a1,rden);
  add4(a0,bb0); add4(a1,bb1);
  if (do_relu){
    a0.x=fmaxf(a0.x,0.f); a0.y=fmaxf(a0.y,0.f); a0.z=fmaxf(a0.z,0.f); a0.w=fmaxf(a0.w,0.f);
    a1.x=fmaxf(a1.x,0.f); a1.y=fmaxf(a1.y,0.f); a1.z=fmaxf(a1.z,0.f); a1.w=fmaxf(a1.w,0.f);
  }
  float4* o4 = (float4*)out + (size_t)v*16 + o*2;
  o4[0] = a0; o4[1] = a1;
}

// ================= fused MLP 64->64->32->16, split-bf16 MFMA =================
__global__ __launch_bounds__(256,3) void mlp3(
    const float* __restrict__ in,
    const unsigned short* __restrict__ W1Hi, const unsigned short* __restrict__ W1Lo,
    const unsigned short* __restrict__ W2Hi, const unsigned short* __restrict__ W2Lo,
    const unsigned short* __restrict__ W3Hi, const unsigned short* __restrict__ W3Lo,
    const float* __restrict__ b1, const float* __restrict__ b2,
    const float* __restrict__ b3, float* __restrict__ out){
  __shared__ __align__(16) unsigned short sW1[2][4096];
  __shared__ __align__(16) unsigned short sW2[2][2048];
  __shared__ __align__(16) unsigned short sW3[2][512];
  __shared__ float sH1[64*68];
  __shared__ float sH2[64*36];
  int t = threadIdx.x;
  int row0 = blockIdx.x * 64;
  int w = t >> 6, l = t & 63;
  int lr = l & 15, lg = l >> 4;
  {
#pragma unroll
    for (int i = 0; i < 2; i++){
      int c = t + i*256;
      int row = c >> 3, slot = c & 7;
      int addr = row*64 + ((slot ^ (row & 7)) << 3);
      *(ushort8v*)&sW1[0][addr] = ((const ushort8v*)W1Hi)[c];
      *(ushort8v*)&sW1[1][addr] = ((const ushort8v*)W1Lo)[c];
    }
    {
      int c = t;
      int row = c >> 3, slot = c & 7;
      int addr = row*64 + ((slot ^ (row & 7)) << 3);
      *(ushort8v*)&sW2[0][addr] = ((const ushort8v*)W2Hi)[c];
      *(ushort8v*)&sW2[1][addr] = ((const ushort8v*)W2Lo)[c];
    }
    if (t < 64){
      int row = t >> 2, slot = t & 3;
      int addr = row*32 + ((slot ^ (row & 3)) << 3);
      *(ushort8v*)&sW3[0][addr] = ((const ushort8v*)W3Hi)[t];
      *(ushort8v*)&sW3[1][addr] = ((const ushort8v*)W3Lo)[t];
    }
  }
  frag_t ax_hi[2], ax_lo[2];
  {
    int grow = row0 + w*16 + lr;
#pragma unroll
    for (int kt = 0; kt < 2; kt++){
      float vals[8];
      const float* p = in + (size_t)grow*64 + kt*32 + lg*8;
      *(float4*)&vals[0] = *(const float4*)p;
      *(float4*)&vals[4] = *(const float4*)(p + 4);
      split8(vals, ax_hi[kt], ax_lo[kt]);
    }
  }
  __syncthreads();
#pragma unroll
  for (int ct = 0; ct < 4; ct++){
    int wrow = ct*16 + lr;
    float bv = b1[wrow];
    f32x4 acc = {bv, bv, bv, bv};
#pragma unroll
    for (int kt = 0; kt < 2; kt++){
      int sl = wrow*64 + (((kt*4 + lg) ^ (wrow & 7)) << 3);
      frag_t bh = __builtin_bit_cast(frag_t, *(const ushort8v*)&sW1[0][sl]);
      frag_t bl = __builtin_bit_cast(frag_t, *(const ushort8v*)&sW1[1][sl]);
      acc = MFMA(ax_hi[kt], bh, acc);
      acc = MFMA(ax_lo[kt], bh, acc);
      acc = MFMA(ax_hi[kt], bl, acc);
    }
#pragma unroll
    for (int r = 0; r < 4; r++)
      sH1[(w*16 + lg*4 + r)*68 + wrow] = fmaxf(acc[r], 0.f);
  }
  frag_t a2_hi[2], a2_lo[2];
#pragma unroll
  for (int kt = 0; kt < 2; kt++){
    float vals[8];
    const float* p = &sH1[(w*16 + lr)*68 + kt*32 + lg*8];
    *(float4*)&vals[0] = *(const float4*)p;
    *(float4*)&vals[4] = *(const float4*)(p + 4);
    split8(vals, a2_hi[kt], a2_lo[kt]);
  }
#pragma unroll
  for (int ct = 0; ct < 2; ct++){
    int wrow = ct*16 + lr;
    float bv = b2[wrow];
    f32x4 acc = {bv, bv, bv, bv};
#pragma unroll
    for (int kt = 0; kt < 2; kt++){
      int sl = wrow*64 + (((kt*4 + lg) ^ (wrow & 7)) << 3);
      frag_t bh = __builtin_bit_cast(frag_t, *(const ushort8v*)&sW2[0][sl]);
      frag_t bl = __builtin_bit_cast(frag_t, *(const ushort8v*)&sW2[1][sl]);
      acc = MFMA(a2_hi[kt], bh, acc);
      acc = MFMA(a2_lo[kt], bh, acc);
      acc = MFMA(a2_hi[kt], bl, acc);
    }
#pragma unroll
    for (int r = 0; r < 4; r++)
      sH2[(w*16 + lg*4 + r)*36 + wrow] = fmaxf(acc[r], 0.f);
  }
  frag_t a3_hi, a3_lo;
  {
    float vals[8];
    const float* p = &sH2[(w*16 + lr)*36 + lg*8];
    *(float4*)&vals[0] = *(const float4*)p;
    *(float4*)&vals[4] = *(const float4*)(p + 4);
    split8(vals, a3_hi, a3_lo);
  }
  {
    float bv = b3[lr];
    f32x4 acc = {bv, bv, bv, bv};
    int sl = lr*32 + ((lg ^ (lr & 3)) << 3);
    frag_t bh = __builtin_bit_cast(frag_t, *(const ushort8v*)&sW3[0][sl]);
    frag_t bl = __builtin_bit_cast(frag_t, *(const ushort8v*)&sW3[1][sl]);
    acc = MFMA(a3_hi, bh, acc);
    acc = MFMA(a3_lo, bh, acc);
    acc = MFMA(a3_hi, bl, acc);
#pragma unroll
    for (int r = 0; r < 4; r++)
      out[(size_t)(row0 + w*16 + lg*4 + r)*16 + lr] = acc[r];
  }
}

extern "C" void kernel_launch(void* const* d_in, const int* in_sizes, int n_in,
                              void* d_out, int out_size, void* d_ws, size_t ws_size,
                              hipStream_t stream) {
    const float* x        = (const float*)d_in[0];
    const int*   ei       = (const int*)d_in[1];
    const float* sage_Wl  = (const float*)d_in[2];
    const float* sage_Wr  = (const float*)d_in[3];
    const float* sage_b   = (const float*)d_in[4];
    const float* gat_W    = (const float*)d_in[5];
    const float* gat_as   = (const float*)d_in[6];
    const float* gat_ad   = (const float*)d_in[7];
    const float* gat_b    = (const float*)d_in[8];
    const float* p1W = (const float*)d_in[9],  *p1b = (const float*)d_in[10];
    const float* p2W = (const float*)d_in[11], *p2b = (const float*)d_in[12];
    const float* p3W = (const float*)d_in[13], *p3b = (const float*)d_in[14];

    int n = in_sizes[0] / 64;        // 262144 = 2^18
    int E = in_sizes[1] / 2;         // 1048576
    const int* src = ei;
    const int* dst = ei + E;

    size_t N64 = (size_t)n * 64;
    float* bufA     = (float*)d_ws;
    float* bufB     = bufA + N64;
    int*   rowptr   = (int*)(bufB + N64);        // n+4
    int*   col      = rowptr + (n + 4);          // E
    unsigned* rec   = (unsigned*)(col + E);      // E
    int*   bcnt     = (int*)(rec + E);           // 256
    int*   boff     = bcnt + 256;                // 257 (+pad)
    int*   bcur     = boff + 260;                // 256
    float* asv      = (float*)(bcur + 256);
    float* adv      = asv + n;
    unsigned short* whi = (unsigned short*)(adv + n);
    unsigned short* wlo = whi + 51712;

    int nbk = (E + 4095) / 4096;     // 256 edge-blocks
    int nbu = n / 1024;              // 256 buckets

    // ---- CSR build (bucketed) ----
    hipMemsetAsync(bcnt, 0, 256 * 4, stream);
    bucket_hist<<<nbk, 256, 0, stream>>>(dst, bcnt, E);
    bucket_scan<<<1, 256, 0, stream>>>(bcnt, boff, bcur);
    bucket_scatter<<<nbk, 256, 0, stream>>>(src, dst, bcur, rec, E);
    bucket_fill<<<nbu, 256, 0, stream>>>(rec, boff, rowptr, col);

    // ---- weight pre-split ----
    prep_weights<<<202, 256, 0, stream>>>(sage_Wl, sage_Wr, gat_W, p1W, p2W, p3W,
                                          whi, wlo);

    // ---- 4 SAGE layers ----
    const float* cur = x;
    float* nxt = bufA;
    for (int l = 0; l < 4; l++){
        sage_mfma<<<n / 64, 256, 0, stream>>>(cur, rowptr, col,
            whi + l*4096,          wlo + l*4096,
            whi + 16384 + l*4096,  wlo + 16384 + l*4096,
            sage_b + l*64, nxt, l < 3 ? 1 : 0);
        cur = nxt;
        nxt = (nxt == bufA) ? bufB : bufA;
    }
    // cur = bufB, h buffer = bufA

    // ---- 3 GAT layers ----
    for (int l = 0; l < 3; l++){
        gat_mfma<<<n / 64, 256, 0, stream>>>(cur,
            whi + 32768 + l*4096, wlo + 32768 + l*4096,
            gat_as + l*64, gat_ad + l*64, nxt, asv, adv);
        gat_agg<<<n / 32, 256, 0, stream>>>(nxt, rowptr, col, asv, adv,
            gat_b + l*64, (float*)cur, l < 2 ? 1 : 0);
    }

    // ---- projection MLP (split-bf16 MFMA) ----
    mlp3<<<n / 64, 256, 0, stream>>>(cur,
        whi + 45056, wlo + 45056,
        whi + 49152, wlo + 49152,
        whi + 51200, wlo + 51200,
        p1b, p2b, p3b, (float*)d_out);
}

// Round 13
// 585.100 us; speedup vs baseline: 1.1425x; 1.0025x over previous
//
#include <hip/hip_runtime.h>
#include <type_traits>
#include <utility>

typedef __attribute__((ext_vector_type(4))) float f32x4;
typedef __attribute__((ext_vector_type(8))) short short8v;
typedef __attribute__((ext_vector_type(8))) unsigned short ushort8v;
typedef __attribute__((ext_vector_type(8))) __bf16 bf16x8;

template<typename T, typename = void> struct can_mfma : std::false_type {};
template<typename T> struct can_mfma<T, std::void_t<decltype(
  __builtin_amdgcn_mfma_f32_16x16x32_bf16(std::declval<T>(), std::declval<T>(),
                                          std::declval<f32x4>(), 0, 0, 0))>>
  : std::true_type {};
using frag_t = std::conditional_t<can_mfma<short8v>::value, short8v, bf16x8>;

__device__ __forceinline__ f32x4 MFMA(frag_t a, frag_t b, f32x4 c){
  return __builtin_amdgcn_mfma_f32_16x16x32_bf16(a, b, c, 0, 0, 0);
}

__device__ __forceinline__ unsigned short bfrn(float x){
  unsigned u = __float_as_uint(x);
  return (unsigned short)((u + 0x7FFFu + ((u >> 16) & 1u)) >> 16);
}
__device__ __forceinline__ float bf2f(unsigned short h){
  return __uint_as_float(((unsigned)h) << 16);
}
__device__ __forceinline__ float lrelu(float v){ return v > 0.f ? v : 0.2f*v; }
__device__ __forceinline__ void add4(float4& a, const float4 v){
  a.x += v.x; a.y += v.y; a.z += v.z; a.w += v.w; }
__device__ __forceinline__ void fma4(float4& a, float w, const float4 v){
  a.x += w*v.x; a.y += w*v.y; a.z += w*v.z; a.w += w*v.w; }
__device__ __forceinline__ void mul4(float4& a, float w){
  a.x *= w; a.y *= w; a.z *= w; a.w *= w; }

// split 8 fp32 -> hi/lo bf16 fragments
__device__ __forceinline__ void split8(const float* vals, frag_t& fh, frag_t& fl){
  union { unsigned short u[8]; ushort8v v; } Uh, Ul;
#pragma unroll
  for (int j = 0; j < 8; j++){
    unsigned short hb = bfrn(vals[j]);
    Uh.u[j] = hb;
    Ul.u[j] = bfrn(vals[j] - bf2f(hb));
  }
  fh = __builtin_bit_cast(frag_t, Uh.v);
  fl = __builtin_bit_cast(frag_t, Ul.v);
}

// ================= CSR build: locality-bucketed (256 buckets x 1024 nodes) ====
// record = src | ((dst & 1023) << 18)   (n = 2^18)

__global__ void bucket_hist(const int* __restrict__ dst, int* __restrict__ bcnt, int E){
  __shared__ int h[256];
  int t = threadIdx.x;
  h[t] = 0; __syncthreads();
  int base = blockIdx.x * 4096;
#pragma unroll
  for (int i = 0; i < 16; i++){
    int e = base + t + i*256;
    if (e < E) atomicAdd(&h[dst[e] >> 10], 1);
  }
  __syncthreads();
  atomicAdd(&bcnt[t], h[t]);
}

__global__ void bucket_scan(const int* __restrict__ bcnt, int* __restrict__ boff,
                            int* __restrict__ bcur){
  __shared__ int s[256];
  int t = threadIdx.x;
  int v = bcnt[t];
  s[t] = v; __syncthreads();
  for (int off=1; off<256; off<<=1){
    int a = (t>=off)? s[t-off] : 0; __syncthreads();
    s[t] += a; __syncthreads();
  }
  boff[t+1] = s[t];
  bcur[t] = s[t] - v;
  if (t == 0) boff[0] = 0;
}

__global__ void bucket_scatter(const int* __restrict__ src, const int* __restrict__ dst,
                               int* __restrict__ bcur, unsigned* __restrict__ rec, int E){
  __shared__ int h[256], hb[256];
  int t = threadIdx.x;
  h[t] = 0; __syncthreads();
  int base = blockIdx.x * 4096;
#pragma unroll
  for (int i = 0; i < 16; i++){
    int e = base + t + i*256;
    if (e < E) atomicAdd(&h[dst[e] >> 10], 1);
  }
  __syncthreads();
  hb[t] = atomicAdd(&bcur[t], h[t]);
  h[t] = 0;
  __syncthreads();
#pragma unroll
  for (int i = 0; i < 16; i++){
    int e = base + t + i*256;
    if (e < E){
      int d = dst[e];
      int b = d >> 10;
      int lp = atomicAdd(&h[b], 1);
      rec[hb[b] + lp] = (unsigned)src[e] | ((unsigned)(d & 1023) << 18);
    }
  }
}

__global__ __launch_bounds__(256) void bucket_fill(
    const unsigned* __restrict__ rec, const int* __restrict__ boff,
    int* __restrict__ rowptr, int* __restrict__ col){
  __shared__ int cnt[1024];
  __shared__ int stmp[256];
  int t = threadIdx.x;
  int b = blockIdx.x;
  int base = boff[b];
  int m = boff[b+1] - base;
#pragma unroll
  for (int i = 0; i < 4; i++) cnt[t*4+i] = 0;
  __syncthreads();
  for (int j = t; j < m; j += 256)
    atomicAdd(&cnt[rec[base+j] >> 18], 1);
  __syncthreads();
  int c0=cnt[t*4], c1=cnt[t*4+1], c2=cnt[t*4+2], c3=cnt[t*4+3];
  int s = c0+c1+c2+c3;
  stmp[t] = s; __syncthreads();
  for (int off=1; off<256; off<<=1){
    int a = (t>=off)? stmp[t-off] : 0; __syncthreads();
    stmp[t] += a; __syncthreads();
  }
  int excl = stmp[t] - s;
  int e0 = excl, e1 = e0+c0, e2 = e1+c1, e3 = e2+c2;
  cnt[t*4]=e0; cnt[t*4+1]=e1; cnt[t*4+2]=e2; cnt[t*4+3]=e3;
  int vbase = b*1024 + t*4;
  rowptr[vbase+1] = base + e1;
  rowptr[vbase+2] = base + e2;
  rowptr[vbase+3] = base + e3;
  rowptr[vbase+4] = base + e3 + c3;
  if (b == 0 && t == 0) rowptr[0] = 0;
  __syncthreads();
  for (int j = t; j < m; j += 256){
    unsigned r = rec[base+j];
    int d = r >> 18;
    int p = atomicAdd(&cnt[d], 1);
    col[base + p] = (int)(r & 0x3FFFFu);
  }
}

// ================= weight pre-split: fp32 -> bf16 hi/lo =================
__global__ void prep_weights(const float* __restrict__ Wl, const float* __restrict__ Wr,
                             const float* __restrict__ Wg, const float* __restrict__ P1,
                             const float* __restrict__ P2, const float* __restrict__ P3,
                             unsigned short* __restrict__ hi, unsigned short* __restrict__ lo){
  int i = blockIdx.x*256 + threadIdx.x;
  if (i >= 51712) return;
  float v;
  if (i < 16384) v = Wl[i];
  else if (i < 32768) v = Wr[i-16384];
  else if (i < 45056) v = Wg[i-32768];
  else if (i < 49152) v = P1[i-45056];
  else if (i < 51200) v = P2[i-49152];
  else v = P3[i-51200];
  unsigned short hb = bfrn(v);
  hi[i] = hb;
  lo[i] = bfrn(v - bf2f(hb));
}

// ================= SAGE: gather-mean + shfl transpose + split-bf16 MFMA =======
// LDS = weights only (32768 B exactly) -> 5 blocks/CU.
// Gather lane (r16=l>>2, q=l&3): feats [q*8,q*8+8) and [32+q*8,...+8) of row w*16+r16,
// packed (hi<<16|lo). MFMA lane (lr,lg) frag kt elem j <- lane lr*4+lg, reg kt*8+j.
__global__ __launch_bounds__(256,5) void sage_mfma(
    const float* __restrict__ cur, const int* __restrict__ rowptr,
    const int* __restrict__ col,
    const unsigned short* __restrict__ WlHi, const unsigned short* __restrict__ WlLo,
    const unsigned short* __restrict__ WrHi, const unsigned short* __restrict__ WrLo,
    const float* __restrict__ bias, float* __restrict__ out, int do_relu){
  __shared__ __align__(16) unsigned short sW[4][4096];   // 32768 B exactly
  int t = threadIdx.x;
  int row0 = blockIdx.x * 64;
  int w = t >> 6, l = t & 63;
  int lr = l & 15, lg = l >> 4;
  // ---- stage 4 weight planes (overlaps gather; single barrier before MFMA) ----
  {
    const ushort8v* g0 = (const ushort8v*)WlHi;
    const ushort8v* g1 = (const ushort8v*)WlLo;
    const ushort8v* g2 = (const ushort8v*)WrHi;
    const ushort8v* g3 = (const ushort8v*)WrLo;
#pragma unroll
    for (int i = 0; i < 2; i++){
      int c = t + i*256;
      int row = c >> 3, slot = c & 7;
      int addr = row*64 + ((slot ^ (row & 7)) << 3);
      *(ushort8v*)&sW[0][addr] = g0[c];
      *(ushort8v*)&sW[1][addr] = g1[c];
      *(ushort8v*)&sW[2][addr] = g2[c];
      *(ushort8v*)&sW[3][addr] = g3[c];
    }
  }
  // ---- gather-mean into 16 packed regs ----
  unsigned pk[16];
  {
    int r16 = l >> 2, q = l & 3;
    int row = row0 + w*16 + r16;
    int beg = rowptr[row], end = rowptr[row+1];
    const float4* base4 = (const float4*)cur;
    float4 a0 = {0,0,0,0}, a1 = a0, a2 = a0, a3 = a0;
    int j = beg;
    for (; j + 2 <= end; j += 2){
      int s0 = col[j], s1 = col[j+1];
      const float4* p0 = base4 + (size_t)s0*16;
      const float4* p1 = base4 + (size_t)s1*16;
      float4 u0=p0[q*2], u1=p0[q*2+1], u2=p0[8+q*2], u3=p0[9+q*2];
      float4 v0=p1[q*2], v1=p1[q*2+1], v2=p1[8+q*2], v3=p1[9+q*2];
      add4(a0,u0); add4(a1,u1); add4(a2,u2); add4(a3,u3);
      add4(a0,v0); add4(a1,v1); add4(a2,v2); add4(a3,v3);
    }
    if (j < end){
      int s0 = col[j];
      const float4* p0 = base4 + (size_t)s0*16;
      add4(a0,p0[q*2]); add4(a1,p0[q*2+1]); add4(a2,p0[8+q*2]); add4(a3,p0[9+q*2]);
    }
    float rdeg = 1.f / fmaxf((float)(end-beg), 1.f);
    mul4(a0,rdeg); mul4(a1,rdeg); mul4(a2,rdeg); mul4(a3,rdeg);
    float mv[16];
    *(float4*)&mv[0]  = a0; *(float4*)&mv[4]  = a1;
    *(float4*)&mv[8]  = a2; *(float4*)&mv[12] = a3;
#pragma unroll
    for (int f = 0; f < 16; f++){
      unsigned short hb = bfrn(mv[f]);
      unsigned short lb = bfrn(mv[f] - bf2f(hb));
      pk[f] = ((unsigned)hb << 16) | (unsigned)lb;
    }
  }
  // ---- in-wave transpose: build A-mean fragments via shfl ----
  frag_t am_hi[2], am_lo[2];
  {
    int srcl = lr*4 + lg;
#pragma unroll
    for (int kt = 0; kt < 2; kt++){
      union { unsigned short u[8]; ushort8v v; } Uh, Ul;
#pragma unroll
      for (int j = 0; j < 8; j++){
        unsigned v = (unsigned)__shfl((int)pk[kt*8+j], srcl);
        Uh.u[j] = (unsigned short)(v >> 16);
        Ul.u[j] = (unsigned short)(v & 0xFFFFu);
      }
      am_hi[kt] = __builtin_bit_cast(frag_t, Uh.v);
      am_lo[kt] = __builtin_bit_cast(frag_t, Ul.v);
    }
  }
  // ---- A-x fragments: own row slice from global ----
  frag_t ax_hi[2], ax_lo[2];
  {
    int grow = row0 + w*16 + lr;
#pragma unroll
    for (int kt = 0; kt < 2; kt++){
      float vals[8];
      const float* p = cur + (size_t)grow*64 + kt*32 + lg*8;
      *(float4*)&vals[0] = *(const float4*)p;
      *(float4*)&vals[4] = *(const float4*)(p + 4);
      split8(vals, ax_hi[kt], ax_lo[kt]);
    }
  }
  __syncthreads();   // sW ready
  // ---- MFMA GEMM ----
#pragma unroll
  for (int ct = 0; ct < 4; ct++){
    float bv = bias[ct*16 + lr];
    f32x4 acc = {bv, bv, bv, bv};
    int wrow = ct*16 + lr;
#pragma unroll
    for (int kt = 0; kt < 2; kt++){
      int sl = wrow*64 + (((kt*4 + lg) ^ (wrow & 7)) << 3);
      frag_t blh = __builtin_bit_cast(frag_t, *(const ushort8v*)&sW[0][sl]);
      frag_t bll = __builtin_bit_cast(frag_t, *(const ushort8v*)&sW[1][sl]);
      acc = MFMA(am_hi[kt], blh, acc);
      acc = MFMA(am_lo[kt], blh, acc);
      acc = MFMA(am_hi[kt], bll, acc);
      frag_t brh = __builtin_bit_cast(frag_t, *(const ushort8v*)&sW[2][sl]);
      frag_t brl = __builtin_bit_cast(frag_t, *(const ushort8v*)&sW[3][sl]);
      acc = MFMA(ax_hi[kt], brh, acc);
      acc = MFMA(ax_lo[kt], brh, acc);
      acc = MFMA(ax_hi[kt], brl, acc);
    }
#pragma unroll
    for (int r = 0; r < 4; r++){
      float v = acc[r];
      if (do_relu) v = fmaxf(v, 0.f);
      out[(size_t)(row0 + w*16 + lg*4 + r)*64 + ct*16 + lr] = v;
    }
  }
}

// ================= GAT: split-bf16 MFMA GEMM (LDS weights) + attention dots ====
__global__ __launch_bounds__(256,8) void gat_mfma(
    const float* __restrict__ cur,
    const unsigned short* __restrict__ WHi, const unsigned short* __restrict__ WLo,
    const float* __restrict__ a_src, const float* __restrict__ a_dst,
    float* __restrict__ h, float* __restrict__ asv, float* __restrict__ adv){
  __shared__ __align__(16) unsigned short sW[2][4096];
  int t = threadIdx.x;
  int row0 = blockIdx.x * 64;
  int w = t >> 6, l = t & 63;
  int lr = l & 15, lg = l >> 4;
  {
    const ushort8v* g0 = (const ushort8v*)WHi;
    const ushort8v* g1 = (const ushort8v*)WLo;
#pragma unroll
    for (int i = 0; i < 2; i++){
      int c = t + i*256;
      int row = c >> 3, slot = c & 7;
      int addr = row*64 + ((slot ^ (row & 7)) << 3);
      *(ushort8v*)&sW[0][addr] = g0[c];
      *(ushort8v*)&sW[1][addr] = g1[c];
    }
  }
  frag_t ax_hi[2], ax_lo[2];
  {
    int grow = row0 + w*16 + lr;
#pragma unroll
    for (int kt = 0; kt < 2; kt++){
      float vals[8];
      const float* p = cur + (size_t)grow*64 + kt*32 + lg*8;
      *(float4*)&vals[0] = *(const float4*)p;
      *(float4*)&vals[4] = *(const float4*)(p + 4);
      split8(vals, ax_hi[kt], ax_lo[kt]);
    }
  }
  __syncthreads();
  float pav[4] = {0,0,0,0}, pdv[4] = {0,0,0,0};
#pragma unroll
  for (int ct = 0; ct < 4; ct++){
    f32x4 acc = {0,0,0,0};
    int wrow = ct*16 + lr;
#pragma unroll
    for (int kt = 0; kt < 2; kt++){
      int sl = wrow*64 + (((kt*4 + lg) ^ (wrow & 7)) << 3);
      frag_t bh = __builtin_bit_cast(frag_t, *(const ushort8v*)&sW[0][sl]);
      frag_t bl = __builtin_bit_cast(frag_t, *(const ushort8v*)&sW[1][sl]);
      acc = MFMA(ax_hi[kt], bh, acc);
      acc = MFMA(ax_lo[kt], bh, acc);
      acc = MFMA(ax_hi[kt], bl, acc);
    }
    float asc = a_src[ct*16 + lr], adc = a_dst[ct*16 + lr];
#pragma unroll
    for (int r = 0; r < 4; r++){
      float v = acc[r];
      h[(size_t)(row0 + w*16 + lg*4 + r)*64 + ct*16 + lr] = v;
      pav[r] += v * asc;
      pdv[r] += v * adc;
    }
  }
#pragma unroll
  for (int off = 1; off < 16; off <<= 1){
#pragma unroll
    for (int r = 0; r < 4; r++){
      pav[r] += __shfl_xor(pav[r], off);
      pdv[r] += __shfl_xor(pdv[r], off);
    }
  }
  if (lr == 0){
#pragma unroll
    for (int r = 0; r < 4; r++){
      int row = row0 + w*16 + lg*4 + r;
      asv[row] = pav[r];
      adv[row] = pdv[r];
    }
  }
}

// ================= GAT fused softmax-aggregate (inline asv logits, no LDS) =====
__global__ __launch_bounds__(256,7) void gat_agg(
    const float* __restrict__ h, const int* __restrict__ rowptr,
    const int* __restrict__ col, const float* __restrict__ asv,
    const float* __restrict__ adv, const float* __restrict__ bias,
    float* __restrict__ out, int do_relu){
  int t = threadIdx.x;
  int row0 = blockIdx.x * 32;
  int rl = t >> 3;
  int o = t & 7;
  int v = row0 + rl;
  int beg = rowptr[v], end = rowptr[v+1];
  float advv = adv[v];
  float m = lrelu(asv[v] + advv);
  float den = 1.f;
  const float4* hb4 = (const float4*)h;
  const float4* pv = hb4 + (size_t)v*16 + o*2;
  float4 a0 = pv[0], a1 = pv[1];
  for (int j = beg; j < end; j += 4){
    int e1i = end - 1;
    int i1 = j+1 < end ? j+1 : e1i;
    int i2 = j+2 < end ? j+2 : e1i;
    int i3 = j+3 < end ? j+3 : e1i;
    int s0 = col[j], s1 = col[i1], s2 = col[i2], s3 = col[i3];
    float q1 = (j+1<end)?1.f:0.f, q2=(j+2<end)?1.f:0.f, q3=(j+3<end)?1.f:0.f;
    float e0 = lrelu(asv[s0] + advv);
    float e1 = lrelu(asv[s1] + advv);
    float e2 = lrelu(asv[s2] + advv);
    float e3 = lrelu(asv[s3] + advv);
    float cm = fmaxf(fmaxf(e0, e1), fmaxf(e2, e3));
    if (cm > m){
      float sc = expf(m - cm);
      den *= sc; mul4(a0, sc); mul4(a1, sc);
      m = cm;
    }
    float w0 = expf(e0 - m);
    float w1 = q1 * expf(e1 - m);
    float w2 = q2 * expf(e2 - m);
    float w3 = q3 * expf(e3 - m);
    den += w0 + w1 + w2 + w3;
    const float4* p0 = hb4 + (size_t)s0*16 + o*2;
    const float4* p1 = hb4 + (size_t)s1*16 + o*2;
    const float4* p2 = hb4 + (size_t)s2*16 + o*2;
    const float4* p3 = hb4 + (size_t)s3*16 + o*2;
    float4 g00=p0[0], g01=p0[1], g10=p1[0], g11=p1[1];
    float4 g20=p2[0], g21=p2[1], g30=p3[0], g31=p3[1];
    fma4(a0,w0,g00); fma4(a1,w0,g01);
    fma4(a0,w1,g10); fma4(a1,w1,g11);
    fma4(a0,w2,g20); fma4(a1,w2,g21);
    fma4(a0,w3,g30); fma4(a1,w3,g31);
  }
  float rden = 1.f / fmaxf(den, 1e-16f);
  const float4* b4 = (const float4*)bias;
  float4 bb0 = b4[o*2], bb1 = b4[o*2+1];
  mul4(a0,rden); mul4(a1,rden);
  add4(a0,bb0); add4(a1,bb1);
  if (do_relu){
    a0.x=fmaxf(a0.x,0.f); a0.y=fmaxf(a0.y,0.f); a0.z=fmaxf(a0.z,0.f); a0.w=fmaxf(a0.w,0.f);
    a1.x=fmaxf(a1.x,0.f); a1.y=fmaxf(a1.y,0.f); a1.z=fmaxf(a1.z,0.f); a1.w=fmaxf(a1.w,0.f);
  }
  float4* o4 = (float4*)out + (size_t)v*16 + o*2;
  o4[0] = a0; o4[1] = a1;
}

// ================= fused MLP 64->64->32->16, split-bf16 MFMA =================
__global__ __launch_bounds__(256,3) void mlp3(
    const float* __restrict__ in,
    const unsigned short* __restrict__ W1Hi, const unsigned short* __restrict__ W1Lo,
    const unsigned short* __restrict__ W2Hi, const unsigned short* __restrict__ W2Lo,
    const unsigned short* __restrict__ W3Hi, const unsigned short* __restrict__ W3Lo,
    const float* __restrict__ b1, const float* __restrict__ b2,
    const float* __restrict__ b3, float* __restrict__ out){
  __shared__ __align__(16) unsigned short sW1[2][4096];
  __shared__ __align__(16) unsigned short sW2[2][2048];
  __shared__ __align__(16) unsigned short sW3[2][512];
  __shared__ float sH1[64*68];
  __shared__ float sH2[64*36];
  int t = threadIdx.x;
  int row0 = blockIdx.x * 64;
  int w = t >> 6, l = t & 63;
  int lr = l & 15, lg = l >> 4;
  {
#pragma unroll
    for (int i = 0; i < 2; i++){
      int c = t + i*256;
      int row = c >> 3, slot = c & 7;
      int addr = row*64 + ((slot ^ (row & 7)) << 3);
      *(ushort8v*)&sW1[0][addr] = ((const ushort8v*)W1Hi)[c];
      *(ushort8v*)&sW1[1][addr] = ((const ushort8v*)W1Lo)[c];
    }
    {
      int c = t;
      int row = c >> 3, slot = c & 7;
      int addr = row*64 + ((slot ^ (row & 7)) << 3);
      *(ushort8v*)&sW2[0][addr] = ((const ushort8v*)W2Hi)[c];
      *(ushort8v*)&sW2[1][addr] = ((const ushort8v*)W2Lo)[c];
    }
    if (t < 64){
      int row = t >> 2, slot = t & 3;
      int addr = row*32 + ((slot ^ (row & 3)) << 3);
      *(ushort8v*)&sW3[0][addr] = ((const ushort8v*)W3Hi)[t];
      *(ushort8v*)&sW3[1][addr] = ((const ushort8v*)W3Lo)[t];
    }
  }
  frag_t ax_hi[2], ax_lo[2];
  {
    int grow = row0 + w*16 + lr;
#pragma unroll
    for (int kt = 0; kt < 2; kt++){
      float vals[8];
      const float* p = in + (size_t)grow*64 + kt*32 + lg*8;
      *(float4*)&vals[0] = *(const float4*)p;
      *(float4*)&vals[4] = *(const float4*)(p + 4);
      split8(vals, ax_hi[kt], ax_lo[kt]);
    }
  }
  __syncthreads();
#pragma unroll
  for (int ct = 0; ct < 4; ct++){
    int wrow = ct*16 + lr;
    float bv = b1[wrow];
    f32x4 acc = {bv, bv, bv, bv};
#pragma unroll
    for (int kt = 0; kt < 2; kt++){
      int sl = wrow*64 + (((kt*4 + lg) ^ (wrow & 7)) << 3);
      frag_t bh = __builtin_bit_cast(frag_t, *(const ushort8v*)&sW1[0][sl]);
      frag_t bl = __builtin_bit_cast(frag_t, *(const ushort8v*)&sW1[1][sl]);
      acc = MFMA(ax_hi[kt], bh, acc);
      acc = MFMA(ax_lo[kt], bh, acc);
      acc = MFMA(ax_hi[kt], bl, acc);
    }
#pragma unroll
    for (int r = 0; r < 4; r++)
      sH1[(w*16 + lg*4 + r)*68 + wrow] = fmaxf(acc[r], 0.f);
  }
  frag_t a2_hi[2], a2_lo[2];
#pragma unroll
  for (int kt = 0; kt < 2; kt++){
    float vals[8];
    const float* p = &sH1[(w*16 + lr)*68 + kt*32 + lg*8];
    *(float4*)&vals[0] = *(const float4*)p;
    *(float4*)&vals[4] = *(const float4*)(p + 4);
    split8(vals, a2_hi[kt], a2_lo[kt]);
  }
#pragma unroll
  for (int ct = 0; ct < 2; ct++){
    int wrow = ct*16 + lr;
    float bv = b2[wrow];
    f32x4 acc = {bv, bv, bv, bv};
#pragma unroll
    for (int kt = 0; kt < 2; kt++){
      int sl = wrow*64 + (((kt*4 + lg) ^ (wrow & 7)) << 3);
      frag_t bh = __builtin_bit_cast(frag_t, *(const ushort8v*)&sW2[0][sl]);
      frag_t bl = __builtin_bit_cast(frag_t, *(const ushort8v*)&sW2[1][sl]);
      acc = MFMA(a2_hi[kt], bh, acc);
      acc = MFMA(a2_lo[kt], bh, acc);
      acc = MFMA(a2_hi[kt], bl, acc);
    }
#pragma unroll
    for (int r = 0; r < 4; r++)
      sH2[(w*16 + lg*4 + r)*36 + wrow] = fmaxf(acc[r], 0.f);
  }
  frag_t a3_hi, a3_lo;
  {
    float vals[8];
    const float* p = &sH2[(w*16 + lr)*36 + lg*8];
    *(float4*)&vals[0] = *(const float4*)p;
    *(float4*)&vals[4] = *(const float4*)(p + 4);
    split8(vals, a3_hi, a3_lo);
  }
  {
    float bv = b3[lr];
    f32x4 acc = {bv, bv, bv, bv};
    int sl = lr*32 + ((lg ^ (lr & 3)) << 3);
    frag_t bh = __builtin_bit_cast(frag_t, *(const ushort8v*)&sW3[0][sl]);
    frag_t bl = __builtin_bit_cast(frag_t, *(const ushort8v*)&sW3[1][sl]);
    acc = MFMA(a3_hi, bh, acc);
    acc = MFMA(a3_lo, bh, acc);
    acc = MFMA(a3_hi, bl, acc);
#pragma unroll
    for (int r = 0; r < 4; r++)
      out[(size_t)(row0 + w*16 + lg*4 + r)*16 + lr] = acc[r];
  }
}

extern "C" void kernel_launch(void* const* d_in, const int* in_sizes, int n_in,
                              void* d_out, int out_size, void* d_ws, size_t ws_size,
                              hipStream_t stream) {
    const float* x        = (const float*)d_in[0];
    const int*   ei       = (const int*)d_in[1];
    const float* sage_Wl  = (const float*)d_in[2];
    const float* sage_Wr  = (const float*)d_in[3];
    const float* sage_b   = (const float*)d_in[4];
    const float* gat_W    = (const float*)d_in[5];
    const float* gat_as   = (const float*)d_in[6];
    const float* gat_ad   = (const float*)d_in[7];
    const float* gat_b    = (const float*)d_in[8];
    const float* p1W = (const float*)d_in[9],  *p1b = (const float*)d_in[10];
    const float* p2W = (const float*)d_in[11], *p2b = (const float*)d_in[12];
    const float* p3W = (const float*)d_in[13], *p3b = (const float*)d_in[14];

    int n = in_sizes[0] / 64;        // 262144 = 2^18
    int E = in_sizes[1] / 2;         // 1048576
    const int* src = ei;
    const int* dst = ei + E;

    size_t N64 = (size_t)n * 64;
    float* bufA     = (float*)d_ws;
    float* bufB     = bufA + N64;
    int*   rowptr   = (int*)(bufB + N64);        // n+4
    int*   col      = rowptr + (n + 4);          // E
    unsigned* rec   = (unsigned*)(col + E);      // E
    int*   bcnt     = (int*)(rec + E);           // 256
    int*   boff     = bcnt + 256;                // 257 (+pad)
    int*   bcur     = boff + 260;                // 256
    float* asv      = (float*)(bcur + 256);
    float* adv      = asv + n;
    unsigned short* whi = (unsigned short*)(adv + n);
    unsigned short* wlo = whi + 51712;

    int nbk = (E + 4095) / 4096;     // 256 edge-blocks
    int nbu = n / 1024;              // 256 buckets

    // ---- CSR build (bucketed) ----
    hipMemsetAsync(bcnt, 0, 256 * 4, stream);
    bucket_hist<<<nbk, 256, 0, stream>>>(dst, bcnt, E);
    bucket_scan<<<1, 256, 0, stream>>>(bcnt, boff, bcur);
    bucket_scatter<<<nbk, 256, 0, stream>>>(src, dst, bcur, rec, E);
    bucket_fill<<<nbu, 256, 0, stream>>>(rec, boff, rowptr, col);

    // ---- weight pre-split ----
    prep_weights<<<202, 256, 0, stream>>>(sage_Wl, sage_Wr, gat_W, p1W, p2W, p3W,
                                          whi, wlo);

    // ---- 4 SAGE layers ----
    const float* cur = x;
    float* nxt = bufA;
    for (int l = 0; l < 4; l++){
        sage_mfma<<<n / 64, 256, 0, stream>>>(cur, rowptr, col,
            whi + l*4096,          wlo + l*4096,
            whi + 16384 + l*4096,  wlo + 16384 + l*4096,
            sage_b + l*64, nxt, l < 3 ? 1 : 0);
        cur = nxt;
        nxt = (nxt == bufA) ? bufB : bufA;
    }
    // cur = bufB, h buffer = bufA

    // ---- 3 GAT layers ----
    for (int l = 0; l < 3; l++){
        gat_mfma<<<n / 64, 256, 0, stream>>>(cur,
            whi + 32768 + l*4096, wlo + 32768 + l*4096,
            gat_as + l*64, gat_ad + l*64, nxt, asv, adv);
        gat_agg<<<n / 32, 256, 0, stream>>>(nxt, rowptr, col, asv, adv,
            gat_b + l*64, (float*)cur, l < 2 ? 1 : 0);
    }

    // ---- projection MLP (split-bf16 MFMA) ----
    mlp3<<<n / 64, 256, 0, stream>>>(cur,
        whi + 45056, wlo + 45056,
        whi + 49152, wlo + 49152,
        whi + 51200, wlo + 51200,
        p1b, p2b, p3b, (float*)d_out);
}